// Round 1
// 553.819 us; speedup vs baseline: 1.1098x; 1.1098x over previous
//
#include <hip/hip_runtime.h>

#define D_MODEL 512
#define SEQ     4096
#define BATCH   4
#define M_TOT   (BATCH*SEQ)   // 16384
#define NT      (SEQ/32)      // 128 key tiles
#define WS_NEEDED ((size_t)2 * M_TOT * D_MODEL * 2)   // node_bf + nodeT_bf: 32 MiB

typedef float  f32x4  __attribute__((ext_vector_type(4)));
typedef __bf16 bf16x8 __attribute__((ext_vector_type(8)));

union FU { float f; unsigned int u; };
__device__ __forceinline__ unsigned short f_to_bf16(float f) {
    FU c; c.f = f;
    unsigned int r = c.u + 0x7fffu + ((c.u >> 16) & 1u);   // RNE
    return (unsigned short)(r >> 16);
}

// -------- K1: node_bf = relu(x @ W^T + b) (bf16), + transposed copy --------
extern "C" __global__ __launch_bounds__(256) void proj_kernel(
        const float* __restrict__ x, const float* __restrict__ w,
        const float* __restrict__ bias,
        unsigned short* __restrict__ node_bf, unsigned short* __restrict__ nodeT_bf) {
    __shared__ float As[32][68];   // k-major, +4 pad
    __shared__ float Bs[32][68];
    const int tid  = threadIdx.x;
    const int row0 = blockIdx.x * 64;
    const int col0 = blockIdx.y * 64;
    const int m0   = (tid & 15) * 4;
    const int n0   = (tid >> 4) * 4;

    float acc[4][4];
    #pragma unroll
    for (int i = 0; i < 4; ++i)
        #pragma unroll
        for (int j = 0; j < 4; ++j) acc[i][j] = 0.0f;

    for (int kc = 0; kc < D_MODEL; kc += 32) {
        #pragma unroll
        for (int jj = 0; jj < 2; ++jj) {
            int fi = tid + 256*jj;
            int r  = fi >> 3, c4 = (fi & 7) * 4;
            float4 a4 = *(const float4*)(x + (size_t)(row0 + r)*D_MODEL + kc + c4);
            As[c4+0][r] = a4.x; As[c4+1][r] = a4.y; As[c4+2][r] = a4.z; As[c4+3][r] = a4.w;
            float4 b4 = *(const float4*)(w + (size_t)(col0 + r)*D_MODEL + kc + c4);
            Bs[c4+0][r] = b4.x; Bs[c4+1][r] = b4.y; Bs[c4+2][r] = b4.z; Bs[c4+3][r] = b4.w;
        }
        __syncthreads();
        #pragma unroll
        for (int k = 0; k < 32; ++k) {
            float4 a = *(const float4*)&As[k][m0];
            float4 b = *(const float4*)&Bs[k][n0];
            acc[0][0] += a.x*b.x; acc[0][1] += a.x*b.y; acc[0][2] += a.x*b.z; acc[0][3] += a.x*b.w;
            acc[1][0] += a.y*b.x; acc[1][1] += a.y*b.y; acc[1][2] += a.y*b.z; acc[1][3] += a.y*b.w;
            acc[2][0] += a.z*b.x; acc[2][1] += a.z*b.y; acc[2][2] += a.z*b.z; acc[2][3] += a.z*b.w;
            acc[3][0] += a.w*b.x; acc[3][1] += a.w*b.y; acc[3][2] += a.w*b.z; acc[3][3] += a.w*b.w;
        }
        __syncthreads();
    }
    #pragma unroll
    for (int j = 0; j < 4; ++j) {
        float bv = bias[col0 + n0 + j];
        #pragma unroll
        for (int i = 0; i < 4; ++i) {
            float v = acc[i][j] + bv;
            v = v > 0.0f ? v : 0.0f;
            unsigned short us = f_to_bf16(v);
            int row = row0 + m0 + i, col = col0 + n0 + j;
            node_bf[(size_t)row*D_MODEL + col] = us;
            int b = row >> 12, si = row & 4095;
            nodeT_bf[((size_t)(b*D_MODEL + col))*SEQ + si] = us;
        }
    }
}

// -------- K2: flash attention via MFMA, out(fp32) --------
// v2: double-buffered K+V tiles staged with global_load_lds (width 16),
//     next tile issued at top of iter (overlaps whole compute phase),
//     ONE barrier per iteration (was 3), K chunk-XOR swizzle applied via
//     pre-swizzled global source (linear LDS dest required by gload_lds).
// LDS: 2*32*512*2 + 2*512*32*2 + 4*16*40*2 = 65536+65536+5120 = 136192 B
extern "C" __global__ __launch_bounds__(256) void flash_kernel(
        const unsigned short* __restrict__ node,
        const unsigned short* __restrict__ nodeT,
        float* __restrict__ out) {
    __shared__ unsigned short Ks[2][32][512];   // [buf][key][d], 16B chunks XOR-swizzled by (key&7)
    __shared__ unsigned short Vt[2][512][32];   // [buf][d][key], linear (64B rows are bank-uniform)
    __shared__ unsigned short Ps[4][16][40];    // per-wave P tile (qrow x key), +8 pad
    const int tid  = threadIdx.x;
    const int lane = tid & 63;
    const int wv   = tid >> 6;
    const int lr   = lane & 15;
    const int quad = lane >> 4;
    const int bb   = blockIdx.y;
    const int q0   = blockIdx.x * 64;

    const unsigned short* nb  = node  + (size_t)bb * SEQ * D_MODEL;
    const unsigned short* ntb = nodeT + (size_t)bb * D_MODEL * SEQ;

    // Q fragments: A[m=lr][k = t*32 + quad*8 + j]
    bf16x8 qf[16];
    const int qrow = q0 + wv*16 + lr;
    #pragma unroll
    for (int t = 0; t < 16; ++t)
        qf[t] = *reinterpret_cast<const bf16x8*>(&nb[(size_t)qrow*D_MODEL + t*32 + quad*8]);

    f32x4 o[32];
    #pragma unroll
    for (int n = 0; n < 32; ++n) o[n] = (f32x4){0.f,0.f,0.f,0.f};
    float m_run[4] = {-3.0e38f,-3.0e38f,-3.0e38f,-3.0e38f};
    float l_run[4] = {0.f,0.f,0.f,0.f};

    const int krow = wv*8;     // this wave stages K rows krow..krow+7 (1 KiB row per wave-call)
    const int vd0b = wv*128;   // this wave stages V d-rows vd0b..vd0b+127 (16 rows per wave-call)

    // stage tile kt into buffer buf. LDS dest is linear (lane*16B from uniform base);
    // K source address carries the inverse chunk swizzle (slot l holds global chunk l^(row&7)).
    auto stage = [&](int kt, int buf) {
        #pragma unroll
        for (int i = 0; i < 8; ++i) {
            int r = krow + i;
            const unsigned short* g = nb + (size_t)(kt*32 + r)*D_MODEL + ((lane ^ (r & 7)) << 3);
            __builtin_amdgcn_global_load_lds(
                (const __attribute__((address_space(1))) unsigned int*)g,
                (__attribute__((address_space(3))) unsigned int*)&Ks[buf][r][0],
                16, 0, 0);
        }
        #pragma unroll
        for (int i = 0; i < 8; ++i) {
            int d0 = vd0b + i*16;
            int d  = d0 + (lane >> 2);
            const unsigned short* g = ntb + (size_t)d*SEQ + kt*32 + ((lane & 3) << 3);
            __builtin_amdgcn_global_load_lds(
                (const __attribute__((address_space(1))) unsigned int*)g,
                (__attribute__((address_space(3))) unsigned int*)&Vt[buf][d0][0],
                16, 0, 0);
        }
    };

    stage(0, 0);
    __syncthreads();           // drains vmcnt: tile 0 resident

    const int kxor = lr & 7;

    for (int kt = 0; kt < NT; ++kt) {
        const int cur = kt & 1;
        // issue next tile's loads now; they fly under the whole compute phase,
        // drained by the single __syncthreads at the end of this iteration.
        if (kt + 1 < NT) stage(kt + 1, cur ^ 1);

        // S = Q K^T (per wave: 16 qrows x 32 keys); swizzled K read
        f32x4 sacc[2];
        sacc[0] = (f32x4){0.f,0.f,0.f,0.f};
        sacc[1] = (f32x4){0.f,0.f,0.f,0.f};
        #pragma unroll
        for (int t = 0; t < 16; ++t) {
            #pragma unroll
            for (int s = 0; s < 2; ++s) {
                bf16x8 kb = *reinterpret_cast<const bf16x8*>(
                    &Ks[cur][s*16 + lr][(((t<<2)|quad) ^ kxor) << 3]);
                sacc[s] = __builtin_amdgcn_mfma_f32_16x16x32_bf16(qf[t], kb, sacc[s], 0, 0, 0);
            }
        }

        // online softmax; C/D layout: row = quad*4+r, col = lr (m89)
        float alpha[4];
        #pragma unroll
        for (int r = 0; r < 4; ++r) {
            float mx = fmaxf(sacc[0][r], sacc[1][r]);
            #pragma unroll
            for (int off = 1; off < 16; off <<= 1)
                mx = fmaxf(mx, __shfl_xor(mx, off));
            float mnew = fmaxf(m_run[r], mx);
            alpha[r] = __expf(m_run[r] - mnew);
            float p0 = __expf(sacc[0][r] - mnew);
            float p1 = __expf(sacc[1][r] - mnew);
            m_run[r] = mnew;
            float rs = p0 + p1;
            #pragma unroll
            for (int off = 1; off < 16; off <<= 1)
                rs += __shfl_xor(rs, off);
            l_run[r] = l_run[r]*alpha[r] + rs;
            Ps[wv][quad*4 + r][lr]      = (unsigned short)f_to_bf16(p0);
            Ps[wv][quad*4 + r][16 + lr] = (unsigned short)f_to_bf16(p1);
        }
        // skip the 128-mult O-rescale when every alpha is exactly 1.0
        // (multiplying by 1.0f is identity -> skipping is bit-exact)
        bool need = !(alpha[0]==1.f && alpha[1]==1.f && alpha[2]==1.f && alpha[3]==1.f);
        if (__any(need)) {
            #pragma unroll
            for (int n = 0; n < 32; ++n) {
                #pragma unroll
                for (int r = 0; r < 4; ++r) o[n][r] *= alpha[r];
            }
        }
        // P fragment: A[m=lr][k=quad*8+j] (same-wave LDS round trip, no barrier needed)
        bf16x8 pa = *reinterpret_cast<const bf16x8*>(&Ps[wv][lr][quad*8]);

        // PV: all 32 d-blocks from fully-resident V tile
        #pragma unroll
        for (int n = 0; n < 32; ++n) {
            bf16x8 vb = *reinterpret_cast<const bf16x8*>(&Vt[cur][n*16 + lr][quad*8]);
            o[n] = __builtin_amdgcn_mfma_f32_16x16x32_bf16(pa, vb, o[n], 0, 0, 0);
        }

        // single barrier per iteration: drains this iter's LDS reads AND the
        // async gload_lds for tile kt+1 (which had the whole iter to land)
        __syncthreads();
    }

    // epilogue: out = O / l (fp32)
    #pragma unroll
    for (int r = 0; r < 4; ++r) {
        float inv = 1.0f / l_run[r];
        int row = q0 + wv*16 + quad*4 + r;
        float* obase = out + ((size_t)bb * SEQ + row) * D_MODEL;
        #pragma unroll
        for (int n = 0; n < 32; ++n)
            obase[n*16 + lr] = o[n][r] * inv;
    }
}

extern "C" void kernel_launch(void* const* d_in, const int* in_sizes, int n_in,
                              void* d_out, int out_size, void* d_ws, size_t ws_size,
                              hipStream_t stream) {
    const float* x = (const float*)d_in[0];
    const float* w = (const float*)d_in[1];
    const float* b = (const float*)d_in[2];
    float* out = (float*)d_out;
    unsigned short* node_bf  = (unsigned short*)d_ws;
    unsigned short* nodeT_bf = node_bf + (size_t)M_TOT * D_MODEL;
    const size_t out_bytes = (size_t)out_size * 4;

    // canary: if nothing below writes d_out, absmax ~= 48.6
    (void)hipMemsetAsync(d_out, 0x42, out_bytes, stream);

    if (d_ws == 0 || ws_size < WS_NEEDED) {
        (void)hipMemsetAsync(d_out, 0x4F, out_bytes, stream);   // ws sentinel
        return;
    }

    (void)hipGetLastError();
    proj_kernel<<<dim3(M_TOT/64, D_MODEL/64), dim3(256), 0, stream>>>(x, w, b, node_bf, nodeT_bf);
    hipError_t ep = hipGetLastError();
    flash_kernel<<<dim3(SEQ/64, BATCH), dim3(256), 0, stream>>>(node_bf, nodeT_bf, out);
    hipError_t ef = hipGetLastError();

    if (ep != hipSuccess) {
        (void)hipMemsetAsync(d_out, 0x49, out_bytes, stream);   // proj launch fail
    } else if (ef != hipSuccess) {
        (void)hipMemsetAsync(d_out, 0x4B, out_bytes, stream);   // flash launch fail
    }
}

// Round 2
// 542.169 us; speedup vs baseline: 1.1337x; 1.0215x over previous
//
#include <hip/hip_runtime.h>

#define D_MODEL 512
#define SEQ     4096
#define BATCH   4
#define M_TOT   (BATCH*SEQ)   // 16384
#define NT      (SEQ/32)      // 128 key tiles
#define WS_NEEDED ((size_t)2 * M_TOT * D_MODEL * 2)   // node_bf + nodeT_bf: 32 MiB

typedef float  f32x4  __attribute__((ext_vector_type(4)));
typedef __bf16 bf16x8 __attribute__((ext_vector_type(8)));

// lgkm-only barrier: syncs LDS data across waves WITHOUT draining vmcnt,
// so in-flight global_load_lds prefetches survive across it.
#define LGKM_BARRIER() asm volatile("s_waitcnt lgkmcnt(0)\n\ts_barrier" ::: "memory")

union FU { float f; unsigned int u; };
__device__ __forceinline__ unsigned short f_to_bf16(float f) {
    FU c; c.f = f;
    unsigned int r = c.u + 0x7fffu + ((c.u >> 16) & 1u);   // RNE
    return (unsigned short)(r >> 16);
}

// -------- K1: node_bf = relu(x @ W^T + b) (bf16), + transposed copy --------
extern "C" __global__ __launch_bounds__(256) void proj_kernel(
        const float* __restrict__ x, const float* __restrict__ w,
        const float* __restrict__ bias,
        unsigned short* __restrict__ node_bf, unsigned short* __restrict__ nodeT_bf) {
    __shared__ float As[32][68];   // k-major, +4 pad
    __shared__ float Bs[32][68];
    const int tid  = threadIdx.x;
    const int row0 = blockIdx.x * 64;
    const int col0 = blockIdx.y * 64;
    const int m0   = (tid & 15) * 4;
    const int n0   = (tid >> 4) * 4;

    float acc[4][4];
    #pragma unroll
    for (int i = 0; i < 4; ++i)
        #pragma unroll
        for (int j = 0; j < 4; ++j) acc[i][j] = 0.0f;

    for (int kc = 0; kc < D_MODEL; kc += 32) {
        #pragma unroll
        for (int jj = 0; jj < 2; ++jj) {
            int fi = tid + 256*jj;
            int r  = fi >> 3, c4 = (fi & 7) * 4;
            float4 a4 = *(const float4*)(x + (size_t)(row0 + r)*D_MODEL + kc + c4);
            As[c4+0][r] = a4.x; As[c4+1][r] = a4.y; As[c4+2][r] = a4.z; As[c4+3][r] = a4.w;
            float4 b4 = *(const float4*)(w + (size_t)(col0 + r)*D_MODEL + kc + c4);
            Bs[c4+0][r] = b4.x; Bs[c4+1][r] = b4.y; Bs[c4+2][r] = b4.z; Bs[c4+3][r] = b4.w;
        }
        __syncthreads();
        #pragma unroll
        for (int k = 0; k < 32; ++k) {
            float4 a = *(const float4*)&As[k][m0];
            float4 b = *(const float4*)&Bs[k][n0];
            acc[0][0] += a.x*b.x; acc[0][1] += a.x*b.y; acc[0][2] += a.x*b.z; acc[0][3] += a.x*b.w;
            acc[1][0] += a.y*b.x; acc[1][1] += a.y*b.y; acc[1][2] += a.y*b.z; acc[1][3] += a.y*b.w;
            acc[2][0] += a.z*b.x; acc[2][1] += a.z*b.y; acc[2][2] += a.z*b.z; acc[2][3] += a.z*b.w;
            acc[3][0] += a.w*b.x; acc[3][1] += a.w*b.y; acc[3][2] += a.w*b.z; acc[3][3] += a.w*b.w;
        }
        __syncthreads();
    }
    #pragma unroll
    for (int j = 0; j < 4; ++j) {
        float bv = bias[col0 + n0 + j];
        #pragma unroll
        for (int i = 0; i < 4; ++i) {
            float v = acc[i][j] + bv;
            v = v > 0.0f ? v : 0.0f;
            unsigned short us = f_to_bf16(v);
            int row = row0 + m0 + i, col = col0 + n0 + j;
            node_bf[(size_t)row*D_MODEL + col] = us;
            int b = row >> 12, si = row & 4095;
            nodeT_bf[((size_t)(b*D_MODEL + col))*SEQ + si] = us;
        }
    }
}

// -------- K2: flash attention via MFMA, out(fp32) --------
// v3: 8 waves/block (2 waves/SIMD). Wave (qg=w&3, kh=w>>2):
//   QK^T: its 16-key half (16 MFMA); joint row-max via 512B LDS exchange.
//   PV:   its 256-d half (16 MFMA) with the FULL 32-key P (no O merge).
//   l accumulated per-half with shared alpha; summed once at the end.
// Mid-iter barriers are lgkm-only (vmcnt NOT drained) so the top-of-iter
// global_load_lds prefetch spans the whole iteration, drained at the
// single end-of-iter __syncthreads().
// K chunk-swizzle: 16B chunk ^ (row&7); V chunk-swizzle: 16B chunk ^ (d&3)
// (both applied on the global SOURCE address, LDS dest linear — T21).
// LDS: 65536 (Ks) + 65536 (Vt) + 5120 (Ps) + 512 (Sm) = 136704 B
extern "C" __global__ __launch_bounds__(512, 2) void flash_kernel(
        const unsigned short* __restrict__ node,
        const unsigned short* __restrict__ nodeT,
        float* __restrict__ out) {
    __shared__ unsigned short Ks[2][32][512];   // [buf][key][d]
    __shared__ unsigned short Vt[2][512][32];   // [buf][d][key]
    __shared__ unsigned short Ps[4][16][40];    // [qg][qrow][key], +8 pad
    __shared__ float          Sm[4][2][16];     // [qg][kh][row] exchange buffer
    const int tid  = threadIdx.x;
    const int lane = tid & 63;
    const int wv   = tid >> 6;        // 0..7
    const int qg   = wv & 3;          // qrow group
    const int kh   = wv >> 2;         // key half (QK) / d half (PV)
    const int lr   = lane & 15;
    const int quad = lane >> 4;
    const int bb   = blockIdx.y;
    const int q0   = blockIdx.x * 64;

    const unsigned short* nb  = node  + (size_t)bb * SEQ * D_MODEL;
    const unsigned short* ntb = nodeT + (size_t)bb * D_MODEL * SEQ;

    // Q fragments: A[m=lr][k = t*32 + quad*8 + j]
    bf16x8 qf[16];
    const int qrow = q0 + qg*16 + lr;
    #pragma unroll
    for (int t = 0; t < 16; ++t)
        qf[t] = *reinterpret_cast<const bf16x8*>(&nb[(size_t)qrow*D_MODEL + t*32 + quad*8]);

    f32x4 o[16];                      // 16 qrows x 256 d (own half)
    #pragma unroll
    for (int n = 0; n < 16; ++n) o[n] = (f32x4){0.f,0.f,0.f,0.f};
    float m_run[4] = {-3.0e38f,-3.0e38f,-3.0e38f,-3.0e38f};
    float l_run[4] = {0.f,0.f,0.f,0.f};

    // stage tile kt into buffer buf; work split across all 8 waves:
    // each wave: 4 K rows (1 KiB each) + 4 V chunks (16 d-rows each).
    auto stage = [&](int kt, int buf) {
        #pragma unroll
        for (int i = 0; i < 4; ++i) {
            int r = wv*4 + i;
            const unsigned short* g = nb + (size_t)(kt*32 + r)*D_MODEL + ((lane ^ (r & 7)) << 3);
            __builtin_amdgcn_global_load_lds(
                (const __attribute__((address_space(1))) unsigned int*)g,
                (__attribute__((address_space(3))) unsigned int*)&Ks[buf][r][0],
                16, 0, 0);
        }
        #pragma unroll
        for (int i = 0; i < 4; ++i) {
            int d0 = (wv*4 + i) * 16;
            int d  = d0 + (lane >> 2);
            const unsigned short* g = ntb + (size_t)d*SEQ + kt*32 + ((((lane & 3) ^ (d & 3))) << 3);
            __builtin_amdgcn_global_load_lds(
                (const __attribute__((address_space(1))) unsigned int*)g,
                (__attribute__((address_space(3))) unsigned int*)&Vt[buf][d0][0],
                16, 0, 0);
        }
    };

    stage(0, 0);
    __syncthreads();           // drains vmcnt: tile 0 resident

    const int kxor = lr & 7;   // K read swizzle ((kh*16+lr)&7 == lr&7)
    const int vxor = lr & 3;   // V read swizzle ((dblk*16+lr)&3 == lr&3)

    for (int kt = 0; kt < NT; ++kt) {
        const int cur = kt & 1;
        // issue next tile's loads now; they stay in flight across BOTH
        // lgkm-only barriers and drain at the end-of-iter __syncthreads.
        if (kt + 1 < NT) stage(kt + 1, cur ^ 1);

        // S half = Q K^T (16 qrows x own 16 keys); swizzled K read
        f32x4 sacc = (f32x4){0.f,0.f,0.f,0.f};
        #pragma unroll
        for (int t = 0; t < 16; ++t) {
            bf16x8 kb = *reinterpret_cast<const bf16x8*>(
                &Ks[cur][kh*16 + lr][(((t<<2)|quad) ^ kxor) << 3]);
            sacc = __builtin_amdgcn_mfma_f32_16x16x32_bf16(qf[t], kb, sacc, 0, 0, 0);
        }

        // local 16-lane max per row; post onto exchange buffer
        float mx[4];
        #pragma unroll
        for (int r = 0; r < 4; ++r) {
            float m = sacc[r];
            #pragma unroll
            for (int off = 1; off < 16; off <<= 1)
                m = fmaxf(m, __shfl_xor(m, off));
            mx[r] = m;
        }
        if (lr == 0) {
            #pragma unroll
            for (int r = 0; r < 4; ++r) Sm[qg][kh][quad*4 + r] = mx[r];
        }
        LGKM_BARRIER();   // #1: Sm visible (vmcnt untouched)

        // joint max, alpha, P, per-half l
        float alpha[4];
        #pragma unroll
        for (int r = 0; r < 4; ++r) {
            float pm   = Sm[qg][kh ^ 1][quad*4 + r];
            float mnew = fmaxf(m_run[r], fmaxf(mx[r], pm));
            alpha[r]   = __expf(m_run[r] - mnew);
            float p    = __expf(sacc[r] - mnew);
            m_run[r]   = mnew;
            Ps[qg][quad*4 + r][kh*16 + lr] = f_to_bf16(p);
            float rs = p;
            #pragma unroll
            for (int off = 1; off < 16; off <<= 1)
                rs += __shfl_xor(rs, off);
            l_run[r] = l_run[r]*alpha[r] + rs;
        }
        // skip O-rescale when every alpha is exactly 1.0 (bit-exact skip)
        bool need = !(alpha[0]==1.f && alpha[1]==1.f && alpha[2]==1.f && alpha[3]==1.f);
        if (__any(need)) {
            #pragma unroll
            for (int n = 0; n < 16; ++n) {
                #pragma unroll
                for (int r = 0; r < 4; ++r) o[n][r] *= alpha[r];
            }
        }
        LGKM_BARRIER();   // #2: full Ps tile visible (vmcnt untouched)

        // P fragment: A[m=lr][k=quad*8+j], full 32 keys
        bf16x8 pa = *reinterpret_cast<const bf16x8*>(&Ps[qg][lr][quad*8]);

        // PV: own 16 d-blocks (d = kh*256 .. kh*256+255), swizzled V read
        #pragma unroll
        for (int n = 0; n < 16; ++n) {
            int dblk = kh*16 + n;
            bf16x8 vb = *reinterpret_cast<const bf16x8*>(
                &Vt[cur][dblk*16 + lr][(quad ^ vxor) << 3]);
            o[n] = __builtin_amdgcn_mfma_f32_16x16x32_bf16(pa, vb, o[n], 0, 0, 0);
        }

        // single full barrier per iter: drains vmcnt (next tile resident)
        // and closes this iter's LDS reads before buffers are reused.
        __syncthreads();
    }

    // final l = own half + partner half (alpha sequence was shared)
    if (lr == 0) {
        #pragma unroll
        for (int r = 0; r < 4; ++r) Sm[qg][kh][quad*4 + r] = l_run[r];
    }
    __syncthreads();
    #pragma unroll
    for (int r = 0; r < 4; ++r) {
        float l_tot = l_run[r] + Sm[qg][kh ^ 1][quad*4 + r];
        float inv   = 1.0f / l_tot;
        int row = q0 + qg*16 + quad*4 + r;
        float* obase = out + ((size_t)bb * SEQ + row) * D_MODEL;
        #pragma unroll
        for (int n = 0; n < 16; ++n)
            obase[(kh*16 + n)*16 + lr] = o[n][r] * inv;
    }
}

extern "C" void kernel_launch(void* const* d_in, const int* in_sizes, int n_in,
                              void* d_out, int out_size, void* d_ws, size_t ws_size,
                              hipStream_t stream) {
    const float* x = (const float*)d_in[0];
    const float* w = (const float*)d_in[1];
    const float* b = (const float*)d_in[2];
    float* out = (float*)d_out;
    unsigned short* node_bf  = (unsigned short*)d_ws;
    unsigned short* nodeT_bf = node_bf + (size_t)M_TOT * D_MODEL;
    const size_t out_bytes = (size_t)out_size * 4;

    // canary: if nothing below writes d_out, absmax ~= 48.6
    (void)hipMemsetAsync(d_out, 0x42, out_bytes, stream);

    if (d_ws == 0 || ws_size < WS_NEEDED) {
        (void)hipMemsetAsync(d_out, 0x4F, out_bytes, stream);   // ws sentinel
        return;
    }

    (void)hipGetLastError();
    proj_kernel<<<dim3(M_TOT/64, D_MODEL/64), dim3(256), 0, stream>>>(x, w, b, node_bf, nodeT_bf);
    hipError_t ep = hipGetLastError();
    flash_kernel<<<dim3(SEQ/64, BATCH), dim3(512), 0, stream>>>(node_bf, nodeT_bf, out);
    hipError_t ef = hipGetLastError();

    if (ep != hipSuccess) {
        (void)hipMemsetAsync(d_out, 0x49, out_bytes, stream);   // proj launch fail
    } else if (ef != hipSuccess) {
        (void)hipMemsetAsync(d_out, 0x4B, out_bytes, stream);   // flash launch fail
    }
}